// Round 10
// baseline (614.148 us; speedup 1.0000x reference)
//
#include <hip/hip_runtime.h>
#include <cstdint>
#include <cstddef>

// ---------------- problem constants ----------------
#define P_TOT    16384      // B*H*W = 4*64*64
#define CIN      1024
#define CMID     512
#define NA       9
#define NANC     147456     // P_TOT * NA
#define PRE_NMS  6000
#define POST_NMS 300
#define IOU_THR  0.7f
#define NWORDS   94         // ceil(6000/64)
#define NHCOPY   4          // histogram copies (contention spreading)

// output layout (floats): cls_pred | reg_pred | proposals
#define CLS_OFF  0
#define REG_OFF  147456
#define PROP_OFF 737280

// ---------------- workspace layout (bytes) ----------------
// h (33.5 MB) dead after gemm2; aliased by WS_MASK (nmsmat, later).
// histN (1 MB, 4 copies) in the old logits region; zeroed by gemm1
// prologue (stream-ordered before gemm2's decode atomics). wcomb also
// written by gemm1's prologue (was the wprep kernel).
// Lifetimes verified stream-ordered.
#define WS_H        0u          // 16384*512*4   = 33554432
#define WS_MASK     0u          // 6000*94*8     = 4512000   (aliases h)
#define WS_HISTN    33554432u   // 4*65536*4     = 1048576
#define WS_BOXES    36700160u   // 147456*4*4    = 2359296
#define WS_WCOMB    39059456u   // 512*48*4      = 98304
#define WS_META     39321600u   // 64*4          = 256   (meta[0]=cnt, meta[1]=T)
#define WS_COLL     39321856u   // 8192*8        = 65536
#define WS_SBOX     39387392u   // 6000*16       = 96000  -> end ~39.5 MB
#define CAP_COLL    8192

__device__ __forceinline__ int imin(int a, int b) { return a < b ? a : b; }

// async global->LDS, 16B per lane. LDS dest must be wave-uniform base +
// lane*16 -> per-lane pointer linear in thread id.
// UNITS RULE (R8 bug): stride between consecutive calls covering a
// contiguous region = nthreads*4 FLOATS (nthreads*16 bytes). A 64-thread
// block covers 1024 B/call, a 256-thread block 4096 B/call.
__device__ __forceinline__ void gld_lds16f(const float* g, float* l) {
    __builtin_amdgcn_global_load_lds(
        (const __attribute__((address_space(1))) void*)g,
        (__attribute__((address_space(3))) void*)l,
        16, 0, 0);
}

// =====================================================================
// GEMM1: h[16384x512] = relu(feats[16384x1024] @ w_bneck[1024x512] + b)
// fp32 vector GEMM. PRECISION CONTRACT (R1/R2): NMS pipeline is
// ordering-sensitive at ~1e-6 score gaps; per-output fp32 FMA chains
// must stay BIT-EXACT (k ascending, fp32 fmac, never reassociated).
// FROZEN at the R0 structure (128x128 tile, 8x8 micro, BK16, dbuf,
// 2 blocks/CU): R3/R4/R5 re-tilings all failed to beat ~227us ->
// co-limited VALU-issue + LDS-return floor at sustained clock (m07
// ~103 TF). Prologue zeroes histN+meta AND builds wcomb (was wprep):
// gemm1 has exactly 512 blocks = wcomb's 512 rows -> block fb writes
// row fb, col t (t<48), no division. Replaces 3 nodes total.
// Spill sentinel: WRITE_SIZE must stay ~33888 KB (32768 C + 1024 histN
// + 96 wcomb).
// =====================================================================
__global__ __launch_bounds__(256)
__attribute__((amdgpu_waves_per_eu(1, 2)))
void gemm1_kernel(
    const float* __restrict__ A, const float* __restrict__ Bw,
    const float* __restrict__ bias, float* __restrict__ C,
    unsigned int* __restrict__ histN, unsigned int* __restrict__ meta,
    const float* __restrict__ wcls, const float* __restrict__ wreg,
    float* __restrict__ wcomb)
{
    __shared__ float As[2][16][132];   // [buf][k][m] transposed, padded
    __shared__ float Bs[2][16][128];   // [buf][k][n]  (no pad: load_lds linear)

    const int t  = threadIdx.x;

    // ---- prologue writes (all stream-ordered before gemm2):
    // zero histN (1 MB) + meta; build wcomb row fb (k=fb, o=t).
    {
        const int fb = (int)blockIdx.x * 4 + (int)blockIdx.y;  // grid (128,4)
        if (t < 128) {
            uint4* hz = (uint4*)histN;
            hz[fb * 128 + t] = make_uint4(0u, 0u, 0u, 0u);
        }
        if (fb == 0 && t < 64) meta[t] = 0u;
        if (t < 48) {
            float v = 0.f;
            if (t < 9)       v = wcls[fb * 9 + t];
            else if (t < 45) v = wreg[fb * 36 + (t - 9)];
            wcomb[fb * 48 + t] = v;
        }
    }

    const int m0 = blockIdx.x * 128;
    const int n0 = blockIdx.y * 128;
    const int tx = t & 15;             // n-dir: cols tx*4, 64+tx*4
    const int ty = t >> 4;             // m-dir: rows ty*4..+3, 64+ty*4..+3

    const int ar0 = t >> 2;            // A row in tile (0..63), second +64
    const int ac0 = (t & 3) * 4;       // A col in tile (k)

    const float* asrc0 = A + (size_t)(m0 + ar0) * CIN + ac0;
    const float* asrc1 = asrc0 + (size_t)64 * CIN;
    const float* bsrc  = Bw + (size_t)(t >> 5) * CMID + n0 + (t & 31) * 4;
    float* bdst0 = &Bs[0][0][0] + t * 4;   // byte off = 16*t (lane-linear)
    float* bdst1 = &Bs[1][0][0] + t * 4;

    float4 c0a{0,0,0,0}, c0b{0,0,0,0}, c1a{0,0,0,0}, c1b{0,0,0,0};
    float4 c2a{0,0,0,0}, c2b{0,0,0,0}, c3a{0,0,0,0}, c3b{0,0,0,0};
    float4 c4a{0,0,0,0}, c4b{0,0,0,0}, c5a{0,0,0,0}, c5b{0,0,0,0};
    float4 c6a{0,0,0,0}, c6b{0,0,0,0}, c7a{0,0,0,0}, c7b{0,0,0,0};

    // ---- prologue: tile 0 into buf 0 ----
    gld_lds16f(bsrc, bdst0);
    gld_lds16f(bsrc + 8 * CMID, bdst0 + 1024);
    float4 pa0 = *(const float4*)(asrc0);
    float4 pa1 = *(const float4*)(asrc1);
    As[0][ac0 + 0][ar0] = pa0.x; As[0][ac0 + 1][ar0] = pa0.y;
    As[0][ac0 + 2][ar0] = pa0.z; As[0][ac0 + 3][ar0] = pa0.w;
    As[0][ac0 + 0][ar0 + 64] = pa1.x; As[0][ac0 + 1][ar0 + 64] = pa1.y;
    As[0][ac0 + 2][ar0 + 64] = pa1.z; As[0][ac0 + 3][ar0 + 64] = pa1.w;
    __syncthreads();

#define FMA4(acc, s, b) { acc.x += (s)*(b).x; acc.y += (s)*(b).y; \
                          acc.z += (s)*(b).z; acc.w += (s)*(b).w; }

    for (int kt = 0; kt < 64; ++kt) {
        const int cur = kt & 1, nxt = cur ^ 1;
        if (kt < 63) {
            const int k0 = (kt + 1) * 16;
            float* bd = nxt ? bdst1 : bdst0;
            gld_lds16f(bsrc + (size_t)k0 * CMID, bd);
            gld_lds16f(bsrc + (size_t)(k0 + 8) * CMID, bd + 1024);
            pa0 = *(const float4*)(asrc0 + k0);
            pa1 = *(const float4*)(asrc1 + k0);
        }
#pragma unroll 2
        for (int kk = 0; kk < 16; ++kk) {
            float4 a0 = *(const float4*)&As[cur][kk][ty * 4];
            float4 a1 = *(const float4*)&As[cur][kk][64 + ty * 4];
            float4 b0 = *(const float4*)&Bs[cur][kk][tx * 4];
            float4 b1 = *(const float4*)&Bs[cur][kk][64 + tx * 4];
            FMA4(c0a, a0.x, b0) FMA4(c0b, a0.x, b1)
            FMA4(c1a, a0.y, b0) FMA4(c1b, a0.y, b1)
            FMA4(c2a, a0.z, b0) FMA4(c2b, a0.z, b1)
            FMA4(c3a, a0.w, b0) FMA4(c3b, a0.w, b1)
            FMA4(c4a, a1.x, b0) FMA4(c4b, a1.x, b1)
            FMA4(c5a, a1.y, b0) FMA4(c5b, a1.y, b1)
            FMA4(c6a, a1.z, b0) FMA4(c6b, a1.z, b1)
            FMA4(c7a, a1.w, b0) FMA4(c7b, a1.w, b1)
        }
        if (kt < 63) {
            As[nxt][ac0 + 0][ar0] = pa0.x; As[nxt][ac0 + 1][ar0] = pa0.y;
            As[nxt][ac0 + 2][ar0] = pa0.z; As[nxt][ac0 + 3][ar0] = pa0.w;
            As[nxt][ac0 + 0][ar0 + 64] = pa1.x; As[nxt][ac0 + 1][ar0 + 64] = pa1.y;
            As[nxt][ac0 + 2][ar0 + 64] = pa1.z; As[nxt][ac0 + 3][ar0 + 64] = pa1.w;
        }
        __syncthreads();
    }
#undef FMA4

    const float4 bias0 = *(const float4*)(bias + n0 + tx * 4);
    const float4 bias1 = *(const float4*)(bias + n0 + 64 + tx * 4);
#define STROW(row, ca, cb) { \
    float4 o; \
    o.x = fmaxf(ca.x + bias0.x, 0.f); o.y = fmaxf(ca.y + bias0.y, 0.f); \
    o.z = fmaxf(ca.z + bias0.z, 0.f); o.w = fmaxf(ca.w + bias0.w, 0.f); \
    *(float4*)(C + (size_t)(row) * CMID + n0 + tx * 4) = o; \
    o.x = fmaxf(cb.x + bias1.x, 0.f); o.y = fmaxf(cb.y + bias1.y, 0.f); \
    o.z = fmaxf(cb.z + bias1.z, 0.f); o.w = fmaxf(cb.w + bias1.w, 0.f); \
    *(float4*)(C + (size_t)(row) * CMID + n0 + 64 + tx * 4) = o; }

    const int mr = m0 + ty * 4;
    STROW(mr + 0, c0a, c0b)   STROW(mr + 1, c1a, c1b)
    STROW(mr + 2, c2a, c2b)   STROW(mr + 3, c3a, c3b)
    STROW(mr + 64, c4a, c4b)  STROW(mr + 65, c5a, c5b)
    STROW(mr + 66, c6a, c6b)  STROW(mr + 67, c7a, c7b)
#undef STROW
}

// =====================================================================
// GEMM2+DECODE fused (R4 version, measured-good). 32 px/block, grid 512
// -> 2 blocks/CU. Per-output k-chain: kt 0..15 x kk 0..31 ascending ->
// bit-exact. 8 out-groups of 6; wS float2 reads.
// =====================================================================
__global__ __launch_bounds__(256) void gemm2_kernel(
    const float* __restrict__ h, const float* __restrict__ wcomb,
    const float* __restrict__ bcls, const float* __restrict__ breg,
    const float4* __restrict__ ancs, float* __restrict__ out,
    float4* __restrict__ boxes, unsigned int* __restrict__ histN)
{
    __shared__ float hS[32][33];   // padded
    __shared__ float wS[32][48];
    __shared__ float lt[32][49];   // logits tile [px][out], padded

    const int t  = threadIdx.x;
    const int p0 = blockIdx.x * 32;
    const int px = t & 31;
    const int og = t >> 5;          // 0..7 -> outs og*6 .. og*6+5

    const int hr = t >> 3;          // stage row 0..31
    const int hc = (t & 7) * 4;     // stage col

    float acc[6] = {};

    for (int kt = 0; kt < 16; ++kt) {
        const int k0 = kt * 32;
        {   // stage h tile 32x32 (1 float4/thread)
            const float* hp = h + (size_t)(p0 + hr) * CMID + k0 + hc;
            float4 v0 = *(const float4*)(hp);
            hS[hr][hc + 0] = v0.x; hS[hr][hc + 1] = v0.y;
            hS[hr][hc + 2] = v0.z; hS[hr][hc + 3] = v0.w;
        }
        {   // stage w tile 32x48 = 384 float4
            int idx = t;
            if (idx < 384) {
                int kk = idx / 12, o4 = (idx - kk * 12) * 4;
                *(float4*)&wS[kk][o4] = *(const float4*)&wcomb[(size_t)(k0 + kk) * 48 + o4];
            }
            idx = t + 256;
            if (idx < 384) {
                int kk = idx / 12, o4 = (idx - kk * 12) * 4;
                *(float4*)&wS[kk][o4] = *(const float4*)&wcomb[(size_t)(k0 + kk) * 48 + o4];
            }
        }
        __syncthreads();
#pragma unroll 4
        for (int kk = 0; kk < 32; ++kk) {
            float hv = hS[px][kk];
            float2 w0 = *(const float2*)&wS[kk][og * 6];
            float2 w1 = *(const float2*)&wS[kk][og * 6 + 2];
            float2 w2 = *(const float2*)&wS[kk][og * 6 + 4];
            acc[0] += hv * w0.x; acc[1] += hv * w0.y;
            acc[2] += hv * w1.x; acc[3] += hv * w1.y;
            acc[4] += hv * w2.x; acc[5] += hv * w2.y;
        }
        __syncthreads();
    }

    // logits -> LDS (bias added exactly as before)
#pragma unroll
    for (int c = 0; c < 6; ++c) {
        int o = og * 6 + c;
        float v = 0.f;
        if (o < 45) {
            float bv = (o < 9) ? bcls[o] : breg[o - 9];
            v = acc[c] + bv;
        }
        lt[px][o] = v;
    }
    __syncthreads();

    // decode: 288 anchors per block (32 px * 9 a), 256 threads -> <=2 each
#pragma unroll
    for (int rr = 0; rr < 2; ++rr) {
        int a_lin = t + rr * 256;
        if (a_lin < 288) {
            int px_l = a_lin / 9;
            int a    = a_lin - px_l * 9;
            int i    = (p0 + px_l) * 9 + a;

            float lg = lt[px_l][a];
            float score = 1.f / (1.f + expf(-lg));
            out[CLS_OFF + i] = score;

            float r0 = lt[px_l][9 + a * 4 + 0];
            float r1 = lt[px_l][9 + a * 4 + 1];
            float r2 = lt[px_l][9 + a * 4 + 2];
            float r3 = lt[px_l][9 + a * 4 + 3];
            float4 rg; rg.x = r0; rg.y = r1; rg.z = r2; rg.w = r3;
            *(float4*)(out + REG_OFF + (size_t)i * 4) = rg;

            float4 an = ancs[i];
            float cx = an.x + r0 * an.z;
            float cy = an.y + r1 * an.w;
            float ww = an.z * expf(r2);
            float hh = an.w * expf(r3);
            float4 bb;
            bb.x = fminf(fmaxf(cx - ww * 0.5f, 0.f), 1.f);
            bb.y = fminf(fmaxf(cy - hh * 0.5f, 0.f), 1.f);
            bb.z = fminf(fmaxf(cx + ww * 0.5f, 0.f), 1.f);
            bb.w = fminf(fmaxf(cy + hh * 0.5f, 0.f), 1.f);
            boxes[i] = bb;

            unsigned int sb = __float_as_uint(score);   // positive -> bit-monotone
            atomicAdd(&histN[(unsigned)(blockIdx.x & (NHCOPY - 1)) * 65536u + (sb >> 16)], 1u);
        }
    }
}

// =====================================================================
// Scan: find threshold bin T = max bin with cum(>=T) >= PRE_NMS.
// Reads histN's 4 copies directly (hreduce node eliminated; this exact
// structure passed in R6). ~1 MB single-block read ~ +7-10us in-kernel,
// -1 dispatch node.
// =====================================================================
__global__ __launch_bounds__(256) void scan_kernel(
    const unsigned int* __restrict__ histN, unsigned int* __restrict__ meta)
{
    __shared__ unsigned int sums[256];
    __shared__ unsigned int sc[256];
    __shared__ unsigned int sc2[256];
    __shared__ int cstar;
    __shared__ unsigned int saShared;
    __shared__ int tbin;

    int t = threadIdx.x;
    if (t == 0) tbin = -1;

    unsigned int s = 0;
    int base = t << 8;
    for (int c = 0; c < NHCOPY; ++c) {
        const uint4* hp = (const uint4*)(histN + (size_t)c * 65536u + base);
        for (int b = 0; b < 64; ++b) {
            uint4 v = hp[b];
            s += v.x + v.y + v.z + v.w;
        }
    }
    sums[t] = s;
    __syncthreads();

    sc[t] = sums[255 - t];
    __syncthreads();
    for (int off = 1; off < 256; off <<= 1) {
        unsigned int v = sc[t];
        unsigned int add = (t >= off) ? sc[t - off] : 0u;
        __syncthreads();
        sc[t] = v + add;
        __syncthreads();
    }
    {
        unsigned int sa = (t == 255) ? 0u : sc[254 - t];
        if (sa < PRE_NMS && sa + sums[t] >= PRE_NMS) { cstar = t; saShared = sa; }
    }
    __syncthreads();

    int c = cstar;
    unsigned int SA = saShared;
    {
        unsigned int bs = 0;
        int bin = c * 256 + 255 - t;
        for (int cc = 0; cc < NHCOPY; ++cc)
            bs += histN[(size_t)cc * 65536u + bin];
        sc2[t] = bs;
    }
    __syncthreads();
    for (int off = 1; off < 256; off <<= 1) {
        unsigned int v = sc2[t];
        unsigned int add = (t >= off) ? sc2[t - off] : 0u;
        __syncthreads();
        sc2[t] = v + add;
        __syncthreads();
    }
    {
        unsigned int si = sc2[255 - t];
        int cand = (SA + si >= PRE_NMS) ? t : -1;
        atomicMax(&tbin, cand);
    }
    __syncthreads();
    if (t == 0) meta[1] = (unsigned int)(c * 256 + tbin);
}

// =====================================================================
// Collect: all anchors with score bin >= T -> composite sort keys.
// key = score_bits<<32 | (0xFFFFFFFF - idx): larger == (higher score,
// then lower idx) -> matches stable argsort(-score).
// =====================================================================
__global__ __launch_bounds__(256) void collect_kernel(
    const float* __restrict__ scores, const unsigned int* __restrict__ meta,
    unsigned long long* __restrict__ coll, unsigned int* __restrict__ cnt)
{
    int i = blockIdx.x * 256 + threadIdx.x;
    unsigned int T = meta[1];
    unsigned int sb = __float_as_uint(scores[i]);
    if ((sb >> 16) >= T) {
        unsigned int pos = atomicAdd(cnt, 1u);
        if (pos < CAP_COLL)
            coll[pos] = ((unsigned long long)sb << 32) |
                        (unsigned long long)(0xFFFFFFFFu - (unsigned int)i);
    }
}

// =====================================================================
// Rank v3: rank(k) = #{keys > k} (keys unique) -> exact permutation;
// scatter box straight to sorted slot. __ballot = 64 comparisons per
// v_cmp; 512 waves, ~10us wall.
// =====================================================================
__global__ __launch_bounds__(256) void rank_kernel(
    const unsigned long long* __restrict__ coll,
    const unsigned int* __restrict__ cnt,
    const float4* __restrict__ boxes, float4* __restrict__ sboxes)
{
    const int t = threadIdx.x;
    const int lane = t & 63;
    const int gwave = blockIdx.x * 4 + (t >> 6);   // 0..511, 16 me's each
    unsigned int n = cnt[0];
    if (n > CAP_COLL) n = CAP_COLL;
    if (gwave * 16 >= (int)n) return;              // wave-uniform exit

    unsigned long long me[16];
    int rank[16];
#pragma unroll
    for (int i = 0; i < 16; ++i) {
        int mi = gwave * 16 + i;
        me[i] = (mi < (int)n) ? coll[mi] : ~0ULL;  // sentinel: nothing > ~0
        rank[i] = 0;
    }

    for (int j = 0; j < CAP_COLL; j += 64) {
        unsigned long long k = ((unsigned)(j + lane) < n) ? coll[j + lane] : 0ULL;
#pragma unroll
        for (int i = 0; i < 16; ++i)
            rank[i] += (int)__popcll(__ballot(k > me[i]));
    }

#pragma unroll
    for (int i = 0; i < 16; ++i) {
        int mi = gwave * 16 + i;
        // rank[i] is wave-uniform; lane i does this me's gather+store so
        // the 16 box loads issue in parallel across lanes.
        if (mi < (int)n && rank[i] < PRE_NMS && lane == i) {
            unsigned int idx = 0xFFFFFFFFu - (unsigned int)(me[i] & 0xFFFFFFFFULL);
            if (idx > NANC - 1) idx = NANC - 1;   // safety clamp
            sboxes[rank[i]] = boxes[idx];
        }
    }
}

// =====================================================================
// NMS matrix build: strict-upper suppression bitmask.
// mask[r][cb] bit i set <=> j = cb*64+i, j > r, IoU(r,j) > 0.7.
// =====================================================================
__global__ __launch_bounds__(64) void nmsmat_kernel(
    const float4* __restrict__ sboxes, unsigned long long* __restrict__ mask)
{
    const int rb = blockIdx.x, cb = blockIdx.y;
    if (cb < rb) return;
    __shared__ float cx1[64], cy1[64], cx2[64], cy2[64], car[64];

    const int t = threadIdx.x;
    const int c = cb * 64 + t;
    float4 b = (c < PRE_NMS) ? sboxes[c] : make_float4(0.f, 0.f, 0.f, 0.f);
    cx1[t] = b.x; cy1[t] = b.y; cx2[t] = b.z; cy2[t] = b.w;
    car[t] = (b.z - b.x) * (b.w - b.y);
    __syncthreads();

    const int r = rb * 64 + t;
    if (r >= PRE_NMS) return;
    const float4 rbx = sboxes[r];
    const float ra = (rbx.z - rbx.x) * (rbx.w - rbx.y);

    unsigned long long w = 0ULL;
#pragma unroll 8
    for (int i = 0; i < 64; ++i) {
        int j = cb * 64 + i;
        float iw = fmaxf(fminf(rbx.z, cx2[i]) - fmaxf(rbx.x, cx1[i]), 0.f);
        float ih = fmaxf(fminf(rbx.w, cy2[i]) - fmaxf(rbx.y, cy1[i]), 0.f);
        float inter = iw * ih;
        float uni = ra + car[i] - inter;
        float iou = (uni > 0.f) ? (inter / uni) : 0.f;   // dummy j>=6000 -> 0
        if (iou > IOU_THR && j > r) w |= (1ULL << i);
    }
    mask[(size_t)r * NWORDS + cb] = w;
}

// =====================================================================
// NMS resolve v2.1: chunked linear scan (measured: tail dropped ~55us
// in R9 vs the serial-dependent-load version; picks bit-identical).
// Greedy NMS == ascending linear scan; rows staged in 64-row chunks
// (48128 B) into LDS, one vmcnt wait per chunk; fully-suppressed chunks
// skipped with zero loads. Stride = 256 floats/call (64 thr x 16 B).
// =====================================================================
__global__ __launch_bounds__(64) void nmsresolve_kernel(
    const float4* __restrict__ sboxes,
    const unsigned long long* __restrict__ mask,
    float* __restrict__ prop)
{
    __shared__ unsigned long long rowbuf[64 * NWORDS];   // 48128 B
    __shared__ int picks[POST_NMS];

    const int t = threadIdx.x;      // one wave
    for (int j = t; j < POST_NMS * 4; j += 64) prop[j] = 0.f;

    const int w0 = 2 * t, w1 = 2 * t + 1;
    unsigned long long s0 = 0ULL, s1 = 0ULL;    // suppressed words w0, w1
    int cnt = 0;

    for (int c = 0; c < NWORDS && cnt < POST_NMS; ++c) {
        // valid rows of this chunk from accumulated suppression word c
        unsigned long long aw = __shfl((c & 1) ? s1 : s0, c >> 1, 64);
        unsigned long long valid = ~aw;
        if (c == 93) valid &= (1ULL << 48) - 1ULL;   // rows 5952..5999 only
        if (!valid) continue;                         // zero loads

        // bulk-stage chunk c: rows 64c..64c+63 contiguous, 48128 B =
        // 47 calls x 1024 B (64 lanes x 16 B); stride 256 floats/call.
        {
            const float* src = (const float*)(mask + (size_t)c * 64 * NWORDS) + t * 4;
            float* dst = (float*)&rowbuf[0] + t * 4;
#pragma unroll
            for (int k = 0; k < 47; ++k)
                gld_lds16f(src + k * 256, dst + k * 256);
        }
        asm volatile("s_waitcnt vmcnt(0)" ::: "memory");
        __builtin_amdgcn_sched_barrier(0);

        while (valid && cnt < POST_NMS) {
            const int b = __builtin_ctzll(valid);
            if (t == 0) picks[cnt] = c * 64 + b;
            ++cnt;

            // row (64c+b): lane t reads words 2t, 2t+1 from LDS
            unsigned long long rx = 0ULL, ry = 0ULL;
            if (t < 47) {
                ulonglong2 rr = *(const ulonglong2*)&rowbuf[(size_t)b * NWORDS + 2 * t];
                rx = rr.x; ry = rr.y;
            }
            // poison guard: nmsmat only wrote words >= row's chunk (= c)
            unsigned long long m0 = (w0 >= c) ? rx : 0ULL;
            unsigned long long m1 = (w1 >= c) ? ry : 0ULL;
            s0 |= m0; s1 |= m1;
            if (w0 == c) s0 |= (1ULL << b);
            if (w1 == c) s1 |= (1ULL << b);

            // update chunk-local valid: row's word c (strict-upper: only
            // bits > b set) + the pick itself
            unsigned long long wc = __shfl((c & 1) ? m1 : m0, c >> 1, 64);
            valid &= ~wc;
            valid &= ~(1ULL << b);
        }
    }

    __syncthreads();   // drain LDS writes (picks) before gather

    // parallel gather of picked boxes
    for (int i = t; i < cnt; i += 64) {
        float4 bb = sboxes[picks[i]];
        *(float4*)(prop + i * 4) = bb;
    }
}

// =====================================================================
extern "C" void kernel_launch(void* const* d_in, const int* in_sizes, int n_in,
                              void* d_out, int out_size, void* d_ws, size_t ws_size,
                              hipStream_t stream)
{
    const float*  feats   = (const float*)d_in[0];
    const float4* ancs    = (const float4*)d_in[1];
    // d_in[2] = ancs_valid (unused by reference)
    const float*  w_bneck = (const float*)d_in[3];
    const float*  b_bneck = (const float*)d_in[4];
    const float*  w_cls   = (const float*)d_in[5];
    const float*  b_cls   = (const float*)d_in[6];
    const float*  w_reg   = (const float*)d_in[7];
    const float*  b_reg   = (const float*)d_in[8];

    float* out = (float*)d_out;
    char*  ws  = (char*)d_ws;
    float*              h      = (float*)(ws + WS_H);
    float4*             boxes  = (float4*)(ws + WS_BOXES);
    unsigned int*       histN  = (unsigned int*)(ws + WS_HISTN);
    float*              wcomb  = (float*)(ws + WS_WCOMB);
    unsigned int*       meta   = (unsigned int*)(ws + WS_META);
    unsigned long long* coll   = (unsigned long long*)(ws + WS_COLL);
    float4*             sboxes = (float4*)(ws + WS_SBOX);
    unsigned long long* mask   = (unsigned long long*)(ws + WS_MASK); // aliases h

    // 7 nodes (was 9): wprep folded into gemm1 prologue; hreduce into
    // scan. Clean per-node-overhead experiment vs R9's 603.7us.
    gemm1_kernel<<<dim3(128, 4), 256, 0, stream>>>(feats, w_bneck, b_bneck, h,
                                                   histN, meta,
                                                   w_cls, w_reg, wcomb);
    gemm2_kernel<<<512, 256, 0, stream>>>(h, wcomb, b_cls, b_reg,
                                          ancs, out, boxes, histN);
    scan_kernel<<<1, 256, 0, stream>>>(histN, meta);
    collect_kernel<<<576, 256, 0, stream>>>(out, meta, coll, &meta[0]);
    rank_kernel<<<128, 256, 0, stream>>>(coll, meta, boxes, sboxes);
    nmsmat_kernel<<<dim3(94, 94), 64, 0, stream>>>(sboxes, mask);
    nmsresolve_kernel<<<1, 64, 0, stream>>>(sboxes, mask, out + PROP_OFF);
}

// Round 11
// 587.400 us; speedup vs baseline: 1.0455x; 1.0455x over previous
//
#include <hip/hip_runtime.h>
#include <cstdint>
#include <cstddef>

// ---------------- problem constants ----------------
#define P_TOT    16384      // B*H*W = 4*64*64
#define CIN      1024
#define CMID     512
#define NA       9
#define NANC     147456     // P_TOT * NA
#define PRE_NMS  6000
#define POST_NMS 300
#define IOU_THR  0.7f
#define NWORDS   94         // ceil(6000/64)
#define NHCOPY   4          // histogram copies (contention spreading)

// output layout (floats): cls_pred | reg_pred | proposals
#define CLS_OFF  0
#define REG_OFF  147456
#define PROP_OFF 737280

// ---------------- workspace layout (bytes) ----------------
// h (33.5 MB) dead after gemm2; aliased by WS_MASK (nmsmat, later).
// histN (1 MB, 4 copies) zeroed by gemm1 prologue. wcombT [48][512]
// (o-major, k-contiguous) built by gemm1 prologue, lives in the free
// gap between histN and boxes. Lifetimes verified stream-ordered.
#define WS_H        0u          // 16384*512*4   = 33554432
#define WS_MASK     0u          // 6000*94*8     = 4512000   (aliases h)
#define WS_HISTN    33554432u   // 4*65536*4     = 1048576
#define WS_WCOMBT   34603008u   // 48*512*4      = 98304  (gap before boxes)
#define WS_BOXES    36700160u   // 147456*4*4    = 2359296
#define WS_HIST     39059456u   // 65536*4       = 262144
#define WS_META     39321600u   // 64*4          = 256   (meta[0]=cnt, meta[1]=T)
#define WS_COLL     39321856u   // 8192*8        = 65536
#define WS_SBOX     39387392u   // 6000*16       = 96000  -> end ~39.5 MB
#define CAP_COLL    8192

__device__ __forceinline__ int imin(int a, int b) { return a < b ? a : b; }

// async global->LDS, 16B per lane. LDS dest must be wave-uniform base +
// lane*16 -> per-lane pointer linear in thread id.
// UNITS RULE (R8 bug): stride between consecutive calls covering a
// contiguous region = nthreads*4 FLOATS (nthreads*16 bytes). A 64-thread
// block covers 1024 B/call, a 256-thread block 4096 B/call.
__device__ __forceinline__ void gld_lds16f(const float* g, float* l) {
    __builtin_amdgcn_global_load_lds(
        (const __attribute__((address_space(1))) void*)g,
        (__attribute__((address_space(3))) void*)l,
        16, 0, 0);
}

// =====================================================================
// GEMM1: h[16384x512] = relu(feats[16384x1024] @ w_bneck[1024x512] + b)
// fp32 vector GEMM. PRECISION CONTRACT (R1/R2): NMS pipeline is
// ordering-sensitive at ~1e-6 score gaps; per-output fp32 FMA chains
// must stay BIT-EXACT (k ascending, fp32 fmac, never reassociated).
// FROZEN at the R0 structure (128x128 tile, 8x8 micro, BK16, dbuf,
// 2 blocks/CU): R3/R4/R5 re-tilings all failed to beat ~227us ->
// co-limited VALU-issue + LDS-return floor at sustained clock (m07
// ~103 TF). Prologue zeroes histN+meta AND builds wcombT (transposed
// combined cls/reg weights, o-major): gemm1 has exactly 512 blocks =
// wcombT's 512 columns -> block fb writes column fb, row t (t<48).
// Spill sentinel: WRITE_SIZE must stay ~33888 KB.
// =====================================================================
__global__ __launch_bounds__(256)
__attribute__((amdgpu_waves_per_eu(1, 2)))
void gemm1_kernel(
    const float* __restrict__ A, const float* __restrict__ Bw,
    const float* __restrict__ bias, float* __restrict__ C,
    unsigned int* __restrict__ histN, unsigned int* __restrict__ meta,
    const float* __restrict__ wcls, const float* __restrict__ wreg,
    float* __restrict__ wcombT)
{
    __shared__ float As[2][16][132];   // [buf][k][m] transposed, padded
    __shared__ float Bs[2][16][128];   // [buf][k][n]  (no pad: load_lds linear)

    const int t  = threadIdx.x;

    // ---- prologue writes (all stream-ordered before gemm2):
    // zero histN (1 MB) + meta; build wcombT[o][fb] (o = t < 48).
    {
        const int fb = (int)blockIdx.x * 4 + (int)blockIdx.y;  // grid (128,4)
        if (t < 128) {
            uint4* hz = (uint4*)histN;
            hz[fb * 128 + t] = make_uint4(0u, 0u, 0u, 0u);
        }
        if (fb == 0 && t < 64) meta[t] = 0u;
        if (t < 48) {
            float v = 0.f;
            if (t < 9)       v = wcls[fb * 9 + t];
            else if (t < 45) v = wreg[fb * 36 + (t - 9)];
            wcombT[t * CMID + fb] = v;
        }
    }

    const int m0 = blockIdx.x * 128;
    const int n0 = blockIdx.y * 128;
    const int tx = t & 15;             // n-dir: cols tx*4, 64+tx*4
    const int ty = t >> 4;             // m-dir: rows ty*4..+3, 64+ty*4..+3

    const int ar0 = t >> 2;            // A row in tile (0..63), second +64
    const int ac0 = (t & 3) * 4;       // A col in tile (k)

    const float* asrc0 = A + (size_t)(m0 + ar0) * CIN + ac0;
    const float* asrc1 = asrc0 + (size_t)64 * CIN;
    const float* bsrc  = Bw + (size_t)(t >> 5) * CMID + n0 + (t & 31) * 4;
    float* bdst0 = &Bs[0][0][0] + t * 4;   // byte off = 16*t (lane-linear)
    float* bdst1 = &Bs[1][0][0] + t * 4;

    float4 c0a{0,0,0,0}, c0b{0,0,0,0}, c1a{0,0,0,0}, c1b{0,0,0,0};
    float4 c2a{0,0,0,0}, c2b{0,0,0,0}, c3a{0,0,0,0}, c3b{0,0,0,0};
    float4 c4a{0,0,0,0}, c4b{0,0,0,0}, c5a{0,0,0,0}, c5b{0,0,0,0};
    float4 c6a{0,0,0,0}, c6b{0,0,0,0}, c7a{0,0,0,0}, c7b{0,0,0,0};

    // ---- prologue: tile 0 into buf 0 ----
    gld_lds16f(bsrc, bdst0);
    gld_lds16f(bsrc + 8 * CMID, bdst0 + 1024);
    float4 pa0 = *(const float4*)(asrc0);
    float4 pa1 = *(const float4*)(asrc1);
    As[0][ac0 + 0][ar0] = pa0.x; As[0][ac0 + 1][ar0] = pa0.y;
    As[0][ac0 + 2][ar0] = pa0.z; As[0][ac0 + 3][ar0] = pa0.w;
    As[0][ac0 + 0][ar0 + 64] = pa1.x; As[0][ac0 + 1][ar0 + 64] = pa1.y;
    As[0][ac0 + 2][ar0 + 64] = pa1.z; As[0][ac0 + 3][ar0 + 64] = pa1.w;
    __syncthreads();

#define FMA4(acc, s, b) { acc.x += (s)*(b).x; acc.y += (s)*(b).y; \
                          acc.z += (s)*(b).z; acc.w += (s)*(b).w; }

    for (int kt = 0; kt < 64; ++kt) {
        const int cur = kt & 1, nxt = cur ^ 1;
        if (kt < 63) {
            const int k0 = (kt + 1) * 16;
            float* bd = nxt ? bdst1 : bdst0;
            gld_lds16f(bsrc + (size_t)k0 * CMID, bd);
            gld_lds16f(bsrc + (size_t)(k0 + 8) * CMID, bd + 1024);
            pa0 = *(const float4*)(asrc0 + k0);
            pa1 = *(const float4*)(asrc1 + k0);
        }
#pragma unroll 2
        for (int kk = 0; kk < 16; ++kk) {
            float4 a0 = *(const float4*)&As[cur][kk][ty * 4];
            float4 a1 = *(const float4*)&As[cur][kk][64 + ty * 4];
            float4 b0 = *(const float4*)&Bs[cur][kk][tx * 4];
            float4 b1 = *(const float4*)&Bs[cur][kk][64 + tx * 4];
            FMA4(c0a, a0.x, b0) FMA4(c0b, a0.x, b1)
            FMA4(c1a, a0.y, b0) FMA4(c1b, a0.y, b1)
            FMA4(c2a, a0.z, b0) FMA4(c2b, a0.z, b1)
            FMA4(c3a, a0.w, b0) FMA4(c3b, a0.w, b1)
            FMA4(c4a, a1.x, b0) FMA4(c4b, a1.x, b1)
            FMA4(c5a, a1.y, b0) FMA4(c5b, a1.y, b1)
            FMA4(c6a, a1.z, b0) FMA4(c6b, a1.z, b1)
            FMA4(c7a, a1.w, b0) FMA4(c7b, a1.w, b1)
        }
        if (kt < 63) {
            As[nxt][ac0 + 0][ar0] = pa0.x; As[nxt][ac0 + 1][ar0] = pa0.y;
            As[nxt][ac0 + 2][ar0] = pa0.z; As[nxt][ac0 + 3][ar0] = pa0.w;
            As[nxt][ac0 + 0][ar0 + 64] = pa1.x; As[nxt][ac0 + 1][ar0 + 64] = pa1.y;
            As[nxt][ac0 + 2][ar0 + 64] = pa1.z; As[nxt][ac0 + 3][ar0 + 64] = pa1.w;
        }
        __syncthreads();
    }
#undef FMA4

    const float4 bias0 = *(const float4*)(bias + n0 + tx * 4);
    const float4 bias1 = *(const float4*)(bias + n0 + 64 + tx * 4);
#define STROW(row, ca, cb) { \
    float4 o; \
    o.x = fmaxf(ca.x + bias0.x, 0.f); o.y = fmaxf(ca.y + bias0.y, 0.f); \
    o.z = fmaxf(ca.z + bias0.z, 0.f); o.w = fmaxf(ca.w + bias0.w, 0.f); \
    *(float4*)(C + (size_t)(row) * CMID + n0 + tx * 4) = o; \
    o.x = fmaxf(cb.x + bias1.x, 0.f); o.y = fmaxf(cb.y + bias1.y, 0.f); \
    o.z = fmaxf(cb.z + bias1.z, 0.f); o.w = fmaxf(cb.w + bias1.w, 0.f); \
    *(float4*)(C + (size_t)(row) * CMID + n0 + 64 + tx * 4) = o; }

    const int mr = m0 + ty * 4;
    STROW(mr + 0, c0a, c0b)   STROW(mr + 1, c1a, c1b)
    STROW(mr + 2, c2a, c2b)   STROW(mr + 3, c3a, c3b)
    STROW(mr + 64, c4a, c4b)  STROW(mr + 65, c5a, c5b)
    STROW(mr + 66, c6a, c6b)  STROW(mr + 67, c7a, c7b)
#undef STROW
}

// =====================================================================
// GEMM2+DECODE fused, v3 (R11): the old inner loop issued 4 LDS instr
// per 6 FMA (2048 LDS instr/thread) - suspected dominant tail cost.
// v3 reads w from the TRANSPOSED wcombT tile (4 consecutive k per b128,
// broadcast across px lanes -> conflict-free) and hv as float4 (hS rows
// padded to 68 floats = 16B-aligned): 7 LDS instr per 24 FMA (2.3x
// fewer), K-tile 64 (16 barriers vs 32). BIT-EXACT: per output o the
// k-order is kt*64 + q*4 + j ascending (j innermost) = same ascending
// k = 0..511 chain, same fp32 fmac ops as before.
// 32 px/block, grid 512 -> 2 blocks/CU; LDS 27.3 KB.
// =====================================================================
__global__ __launch_bounds__(256) void gemm2_kernel(
    const float* __restrict__ h, const float* __restrict__ wcombT,
    const float* __restrict__ bcls, const float* __restrict__ breg,
    const float4* __restrict__ ancs, float* __restrict__ out,
    float4* __restrict__ boxes, unsigned int* __restrict__ histN)
{
    __shared__ float hS[32][68];   // [px][k] K-tile 64, pad 68 (16B-aligned)
    __shared__ float wT[48][64];   // [o][k] tile (reads broadcast; no pad)
    __shared__ float lt[32][49];   // logits tile [px][out], padded

    const int t  = threadIdx.x;
    const int p0 = blockIdx.x * 32;
    const int px = t & 31;
    const int og = t >> 5;          // 0..7 -> outs og*6 .. og*6+5

    const int hr = t >> 3;          // stage row 0..31
    const int hc = (t & 7) * 8;     // stage col 0,8,..,56

    float acc[6] = {};

    for (int kt = 0; kt < 8; ++kt) {
        const int k0 = kt * 64;
        {   // stage h tile 32x64 (2 float4/thread, coalesced)
            const float* hp = h + (size_t)(p0 + hr) * CMID + k0 + hc;
            float4 v0 = *(const float4*)(hp);
            float4 v1 = *(const float4*)(hp + 4);
            *(float4*)&hS[hr][hc]     = v0;
            *(float4*)&hS[hr][hc + 4] = v1;
        }
        {   // stage wT tile 48x64 = 768 float4, 3/thread
#pragma unroll
            for (int r = 0; r < 3; ++r) {
                int idx = t + r * 256;              // < 768
                int row = idx >> 4, c4 = (idx & 15) * 4;
                *(float4*)&wT[row][c4] =
                    *(const float4*)&wcombT[(size_t)row * CMID + k0 + c4];
            }
        }
        __syncthreads();
#pragma unroll
        for (int q = 0; q < 16; ++q) {
            float4 hv4 = *(const float4*)&hS[px][q * 4];
            float4 w0 = *(const float4*)&wT[og * 6 + 0][q * 4];
            float4 w1 = *(const float4*)&wT[og * 6 + 1][q * 4];
            float4 w2 = *(const float4*)&wT[og * 6 + 2][q * 4];
            float4 w3 = *(const float4*)&wT[og * 6 + 3][q * 4];
            float4 w4 = *(const float4*)&wT[og * 6 + 4][q * 4];
            float4 w5 = *(const float4*)&wT[og * 6 + 5][q * 4];
            const float* hv = (const float*)&hv4;
            const float* p0w = (const float*)&w0;
            const float* p1w = (const float*)&w1;
            const float* p2w = (const float*)&w2;
            const float* p3w = (const float*)&w3;
            const float* p4w = (const float*)&w4;
            const float* p5w = (const float*)&w5;
#pragma unroll
            for (int j = 0; j < 4; ++j) {          // k ascending per output
                float hvj = hv[j];
                acc[0] += hvj * p0w[j];
                acc[1] += hvj * p1w[j];
                acc[2] += hvj * p2w[j];
                acc[3] += hvj * p3w[j];
                acc[4] += hvj * p4w[j];
                acc[5] += hvj * p5w[j];
            }
        }
        __syncthreads();
    }

    // logits -> LDS (bias added exactly as before)
#pragma unroll
    for (int c = 0; c < 6; ++c) {
        int o = og * 6 + c;
        float v = 0.f;
        if (o < 45) {
            float bv = (o < 9) ? bcls[o] : breg[o - 9];
            v = acc[c] + bv;
        }
        lt[px][o] = v;
    }
    __syncthreads();

    // decode: 288 anchors per block (32 px * 9 a), 256 threads -> <=2 each
#pragma unroll
    for (int rr = 0; rr < 2; ++rr) {
        int a_lin = t + rr * 256;
        if (a_lin < 288) {
            int px_l = a_lin / 9;
            int a    = a_lin - px_l * 9;
            int i    = (p0 + px_l) * 9 + a;

            float lg = lt[px_l][a];
            float score = 1.f / (1.f + expf(-lg));
            out[CLS_OFF + i] = score;

            float r0 = lt[px_l][9 + a * 4 + 0];
            float r1 = lt[px_l][9 + a * 4 + 1];
            float r2 = lt[px_l][9 + a * 4 + 2];
            float r3 = lt[px_l][9 + a * 4 + 3];
            float4 rg; rg.x = r0; rg.y = r1; rg.z = r2; rg.w = r3;
            *(float4*)(out + REG_OFF + (size_t)i * 4) = rg;

            float4 an = ancs[i];
            float cx = an.x + r0 * an.z;
            float cy = an.y + r1 * an.w;
            float ww = an.z * expf(r2);
            float hh = an.w * expf(r3);
            float4 bb;
            bb.x = fminf(fmaxf(cx - ww * 0.5f, 0.f), 1.f);
            bb.y = fminf(fmaxf(cy - hh * 0.5f, 0.f), 1.f);
            bb.z = fminf(fmaxf(cx + ww * 0.5f, 0.f), 1.f);
            bb.w = fminf(fmaxf(cy + hh * 0.5f, 0.f), 1.f);
            boxes[i] = bb;

            unsigned int sb = __float_as_uint(score);   // positive -> bit-monotone
            atomicAdd(&histN[(unsigned)(blockIdx.x & (NHCOPY - 1)) * 65536u + (sb >> 16)], 1u);
        }
    }
}

// =====================================================================
// Histogram reduce: hist[b] = sum over 4 copies. (R10 lesson: the
// in-scan single-block 1MB read regressed ~15us; parallel hreduce +
// small-hist scan is measured-better. Restored.)
// =====================================================================
__global__ __launch_bounds__(256) void hreduce_kernel(
    const unsigned int* __restrict__ histN, unsigned int* __restrict__ hist)
{
    int b = blockIdx.x * 256 + threadIdx.x;    // < 65536
    unsigned int s = 0;
#pragma unroll
    for (int c = 0; c < NHCOPY; ++c) s += histN[(unsigned)c * 65536u + b];
    hist[b] = s;
}

// =====================================================================
// Scan: find threshold bin T = max bin with cum(>=T) >= PRE_NMS.
// =====================================================================
__global__ __launch_bounds__(256) void scan_kernel(
    const unsigned int* __restrict__ hist, unsigned int* __restrict__ meta)
{
    __shared__ unsigned int sums[256];
    __shared__ unsigned int sc[256];
    __shared__ unsigned int sc2[256];
    __shared__ int cstar;
    __shared__ unsigned int saShared;
    __shared__ int tbin;

    int t = threadIdx.x;
    if (t == 0) tbin = -1;

    unsigned int s = 0;
    int base = t << 8;
    for (int b = 0; b < 256; b += 4) {
        uint4 v = *(const uint4*)(hist + base + b);
        s += v.x + v.y + v.z + v.w;
    }
    sums[t] = s;
    __syncthreads();

    sc[t] = sums[255 - t];
    __syncthreads();
    for (int off = 1; off < 256; off <<= 1) {
        unsigned int v = sc[t];
        unsigned int add = (t >= off) ? sc[t - off] : 0u;
        __syncthreads();
        sc[t] = v + add;
        __syncthreads();
    }
    {
        unsigned int sa = (t == 255) ? 0u : sc[254 - t];
        if (sa < PRE_NMS && sa + sums[t] >= PRE_NMS) { cstar = t; saShared = sa; }
    }
    __syncthreads();

    int c = cstar;
    unsigned int SA = saShared;
    sc2[t] = hist[c * 256 + 255 - t];
    __syncthreads();
    for (int off = 1; off < 256; off <<= 1) {
        unsigned int v = sc2[t];
        unsigned int add = (t >= off) ? sc2[t - off] : 0u;
        __syncthreads();
        sc2[t] = v + add;
        __syncthreads();
    }
    {
        unsigned int si = sc2[255 - t];
        int cand = (SA + si >= PRE_NMS) ? t : -1;
        atomicMax(&tbin, cand);
    }
    __syncthreads();
    if (t == 0) meta[1] = (unsigned int)(c * 256 + tbin);
}

// =====================================================================
// Collect: all anchors with score bin >= T -> composite sort keys.
// key = score_bits<<32 | (0xFFFFFFFF - idx): larger == (higher score,
// then lower idx) -> matches stable argsort(-score).
// =====================================================================
__global__ __launch_bounds__(256) void collect_kernel(
    const float* __restrict__ scores, const unsigned int* __restrict__ meta,
    unsigned long long* __restrict__ coll, unsigned int* __restrict__ cnt)
{
    int i = blockIdx.x * 256 + threadIdx.x;
    unsigned int T = meta[1];
    unsigned int sb = __float_as_uint(scores[i]);
    if ((sb >> 16) >= T) {
        unsigned int pos = atomicAdd(cnt, 1u);
        if (pos < CAP_COLL)
            coll[pos] = ((unsigned long long)sb << 32) |
                        (unsigned long long)(0xFFFFFFFFu - (unsigned int)i);
    }
}

// =====================================================================
// Rank v3: rank(k) = #{keys > k} (keys unique) -> exact permutation;
// scatter box straight to sorted slot. __ballot = 64 comparisons per
// v_cmp; 512 waves, ~10us wall.
// =====================================================================
__global__ __launch_bounds__(256) void rank_kernel(
    const unsigned long long* __restrict__ coll,
    const unsigned int* __restrict__ cnt,
    const float4* __restrict__ boxes, float4* __restrict__ sboxes)
{
    const int t = threadIdx.x;
    const int lane = t & 63;
    const int gwave = blockIdx.x * 4 + (t >> 6);   // 0..511, 16 me's each
    unsigned int n = cnt[0];
    if (n > CAP_COLL) n = CAP_COLL;
    if (gwave * 16 >= (int)n) return;              // wave-uniform exit

    unsigned long long me[16];
    int rank[16];
#pragma unroll
    for (int i = 0; i < 16; ++i) {
        int mi = gwave * 16 + i;
        me[i] = (mi < (int)n) ? coll[mi] : ~0ULL;  // sentinel: nothing > ~0
        rank[i] = 0;
    }

    for (int j = 0; j < CAP_COLL; j += 64) {
        unsigned long long k = ((unsigned)(j + lane) < n) ? coll[j + lane] : 0ULL;
#pragma unroll
        for (int i = 0; i < 16; ++i)
            rank[i] += (int)__popcll(__ballot(k > me[i]));
    }

#pragma unroll
    for (int i = 0; i < 16; ++i) {
        int mi = gwave * 16 + i;
        // rank[i] is wave-uniform; lane i does this me's gather+store so
        // the 16 box loads issue in parallel across lanes.
        if (mi < (int)n && rank[i] < PRE_NMS && lane == i) {
            unsigned int idx = 0xFFFFFFFFu - (unsigned int)(me[i] & 0xFFFFFFFFULL);
            if (idx > NANC - 1) idx = NANC - 1;   // safety clamp
            sboxes[rank[i]] = boxes[idx];
        }
    }
}

// =====================================================================
// NMS matrix build: strict-upper suppression bitmask.
// mask[r][cb] bit i set <=> j = cb*64+i, j > r, IoU(r,j) > 0.7.
// =====================================================================
__global__ __launch_bounds__(64) void nmsmat_kernel(
    const float4* __restrict__ sboxes, unsigned long long* __restrict__ mask)
{
    const int rb = blockIdx.x, cb = blockIdx.y;
    if (cb < rb) return;
    __shared__ float cx1[64], cy1[64], cx2[64], cy2[64], car[64];

    const int t = threadIdx.x;
    const int c = cb * 64 + t;
    float4 b = (c < PRE_NMS) ? sboxes[c] : make_float4(0.f, 0.f, 0.f, 0.f);
    cx1[t] = b.x; cy1[t] = b.y; cx2[t] = b.z; cy2[t] = b.w;
    car[t] = (b.z - b.x) * (b.w - b.y);
    __syncthreads();

    const int r = rb * 64 + t;
    if (r >= PRE_NMS) return;
    const float4 rbx = sboxes[r];
    const float ra = (rbx.z - rbx.x) * (rbx.w - rbx.y);

    unsigned long long w = 0ULL;
#pragma unroll 8
    for (int i = 0; i < 64; ++i) {
        int j = cb * 64 + i;
        float iw = fmaxf(fminf(rbx.z, cx2[i]) - fmaxf(rbx.x, cx1[i]), 0.f);
        float ih = fmaxf(fminf(rbx.w, cy2[i]) - fmaxf(rbx.y, cy1[i]), 0.f);
        float inter = iw * ih;
        float uni = ra + car[i] - inter;
        float iou = (uni > 0.f) ? (inter / uni) : 0.f;   // dummy j>=6000 -> 0
        if (iou > IOU_THR && j > r) w |= (1ULL << i);
    }
    mask[(size_t)r * NWORDS + cb] = w;
}

// =====================================================================
// NMS resolve v2.1: chunked linear scan (measured: tail dropped ~55us
// in R9 vs the serial-dependent-load version; picks bit-identical).
// Greedy NMS == ascending linear scan; rows staged in 64-row chunks
// (48128 B) into LDS, one vmcnt wait per chunk; fully-suppressed chunks
// skipped with zero loads. Stride = 256 floats/call (64 thr x 16 B).
// =====================================================================
__global__ __launch_bounds__(64) void nmsresolve_kernel(
    const float4* __restrict__ sboxes,
    const unsigned long long* __restrict__ mask,
    float* __restrict__ prop)
{
    __shared__ unsigned long long rowbuf[64 * NWORDS];   // 48128 B
    __shared__ int picks[POST_NMS];

    const int t = threadIdx.x;      // one wave
    for (int j = t; j < POST_NMS * 4; j += 64) prop[j] = 0.f;

    const int w0 = 2 * t, w1 = 2 * t + 1;
    unsigned long long s0 = 0ULL, s1 = 0ULL;    // suppressed words w0, w1
    int cnt = 0;

    for (int c = 0; c < NWORDS && cnt < POST_NMS; ++c) {
        // valid rows of this chunk from accumulated suppression word c
        unsigned long long aw = __shfl((c & 1) ? s1 : s0, c >> 1, 64);
        unsigned long long valid = ~aw;
        if (c == 93) valid &= (1ULL << 48) - 1ULL;   // rows 5952..5999 only
        if (!valid) continue;                         // zero loads

        // bulk-stage chunk c: rows 64c..64c+63 contiguous, 48128 B =
        // 47 calls x 1024 B (64 lanes x 16 B); stride 256 floats/call.
        {
            const float* src = (const float*)(mask + (size_t)c * 64 * NWORDS) + t * 4;
            float* dst = (float*)&rowbuf[0] + t * 4;
#pragma unroll
            for (int k = 0; k < 47; ++k)
                gld_lds16f(src + k * 256, dst + k * 256);
        }
        asm volatile("s_waitcnt vmcnt(0)" ::: "memory");
        __builtin_amdgcn_sched_barrier(0);

        while (valid && cnt < POST_NMS) {
            const int b = __builtin_ctzll(valid);
            if (t == 0) picks[cnt] = c * 64 + b;
            ++cnt;

            // row (64c+b): lane t reads words 2t, 2t+1 from LDS
            unsigned long long rx = 0ULL, ry = 0ULL;
            if (t < 47) {
                ulonglong2 rr = *(const ulonglong2*)&rowbuf[(size_t)b * NWORDS + 2 * t];
                rx = rr.x; ry = rr.y;
            }
            // poison guard: nmsmat only wrote words >= row's chunk (= c)
            unsigned long long m0 = (w0 >= c) ? rx : 0ULL;
            unsigned long long m1 = (w1 >= c) ? ry : 0ULL;
            s0 |= m0; s1 |= m1;
            if (w0 == c) s0 |= (1ULL << b);
            if (w1 == c) s1 |= (1ULL << b);

            // update chunk-local valid: row's word c (strict-upper: only
            // bits > b set) + the pick itself
            unsigned long long wc = __shfl((c & 1) ? m1 : m0, c >> 1, 64);
            valid &= ~wc;
            valid &= ~(1ULL << b);
        }
    }

    __syncthreads();   // drain LDS writes (picks) before gather

    // parallel gather of picked boxes
    for (int i = t; i < cnt; i += 64) {
        float4 bb = sboxes[picks[i]];
        *(float4*)(prop + i * 4) = bb;
    }
}

// =====================================================================
extern "C" void kernel_launch(void* const* d_in, const int* in_sizes, int n_in,
                              void* d_out, int out_size, void* d_ws, size_t ws_size,
                              hipStream_t stream)
{
    const float*  feats   = (const float*)d_in[0];
    const float4* ancs    = (const float4*)d_in[1];
    // d_in[2] = ancs_valid (unused by reference)
    const float*  w_bneck = (const float*)d_in[3];
    const float*  b_bneck = (const float*)d_in[4];
    const float*  w_cls   = (const float*)d_in[5];
    const float*  b_cls   = (const float*)d_in[6];
    const float*  w_reg   = (const float*)d_in[7];
    const float*  b_reg   = (const float*)d_in[8];

    float* out = (float*)d_out;
    char*  ws  = (char*)d_ws;
    float*              h      = (float*)(ws + WS_H);
    float4*             boxes  = (float4*)(ws + WS_BOXES);
    unsigned int*       histN  = (unsigned int*)(ws + WS_HISTN);
    unsigned int*       hist   = (unsigned int*)(ws + WS_HIST);
    float*              wcombT = (float*)(ws + WS_WCOMBT);
    unsigned int*       meta   = (unsigned int*)(ws + WS_META);
    unsigned long long* coll   = (unsigned long long*)(ws + WS_COLL);
    float4*             sboxes = (float4*)(ws + WS_SBOX);
    unsigned long long* mask   = (unsigned long long*)(ws + WS_MASK); // aliases h

    // 8 nodes: wprep+memsets fused into gemm1; hreduce+scan restored
    // (R10: in-scan histN read regressed); gemm2 v3 (transposed w).
    gemm1_kernel<<<dim3(128, 4), 256, 0, stream>>>(feats, w_bneck, b_bneck, h,
                                                   histN, meta,
                                                   w_cls, w_reg, wcombT);
    gemm2_kernel<<<512, 256, 0, stream>>>(h, wcombT, b_cls, b_reg,
                                          ancs, out, boxes, histN);
    hreduce_kernel<<<256, 256, 0, stream>>>(histN, hist);
    scan_kernel<<<1, 256, 0, stream>>>(hist, meta);
    collect_kernel<<<576, 256, 0, stream>>>(out, meta, coll, &meta[0]);
    rank_kernel<<<128, 256, 0, stream>>>(coll, meta, boxes, sboxes);
    nmsmat_kernel<<<dim3(94, 94), 64, 0, stream>>>(sboxes, mask);
    nmsresolve_kernel<<<1, 64, 0, stream>>>(sboxes, mask, out + PROP_OFF);
}